// Round 2
// baseline (1740.046 us; speedup 1.0000x reference)
//
#include <hip/hip_runtime.h>

typedef unsigned short u16;
typedef unsigned int u32;

#define Nn 100000
#define Ee 500000
#define DIM 160

__device__ __forceinline__ float bf2f(u16 u) {
    return __uint_as_float(((u32)u) << 16);
}
__device__ __forceinline__ u16 f2bf(float f) {
    u32 i = __float_as_uint(f);
    return (u16)((i + 0x7FFFu + ((i >> 16) & 1u)) >> 16);
}

// ---------------- K1: edge scatter (segment_sum, pre-scaled by 1/sqrt(5)) ----
__global__ __launch_bounds__(256) void scatter_k(const float* __restrict__ em,
                                                 const int* __restrict__ ei,
                                                 float* __restrict__ msg) {
    int tid = blockIdx.x * 256 + threadIdx.x;
    if (tid >= Ee * 40) return;
    int e = tid / 40;
    int k = tid - e * 40;           // 40 quads of 4 floats per 160-wide row
    int dst = ei[Ee + e];           // edge_index row 1 (dst)
    const float4 v = *reinterpret_cast<const float4*>(em + (size_t)e * DIM + k * 4);
    float* q = msg + (size_t)dst * DIM + k * 4;
    const float s = 0.4472135954999579f; // 1/sqrt(5)
    atomicAdd(q + 0, v.x * s);
    atomicAdd(q + 1, v.y * s);
    atomicAdd(q + 2, v.z * s);
    atomicAdd(q + 3, v.w * s);
}

// ---------------- K2/K3: transpose [N][160] f32 -> [160][N] bf16 -------------
__global__ void transpose_f2b_k(const float* __restrict__ in, u16* __restrict__ outp) {
    __shared__ float t[32][33];
    int r0 = blockIdx.x * 32, c0 = blockIdx.y * 32;
    int tx = threadIdx.x, ty = threadIdx.y;
    t[ty][tx] = in[(size_t)(r0 + ty) * DIM + c0 + tx];
    __syncthreads();
    outp[(size_t)(c0 + ty) * Nn + r0 + tx] = f2bf(t[tx][ty]);
}

// ---------------- K4: pre-scale + fuse all weight factors (f32 in, f32 out) --
// Layout in W (f32): Wls' [96][96] @0, Wlv' [96][32] @9216, W000' [64][96] @12288,
//                    W110' [32][96] @18432, W011' [64][32] @21504, W101' [32][32] @23552
__global__ __launch_bounds__(256) void prep_weights_k(
    const float* __restrict__ Wls, const float* __restrict__ Wlv,
    const float* __restrict__ W000, const float* __restrict__ W110,
    const float* __restrict__ W011, const float* __restrict__ W101,
    const float* __restrict__ w00, const float* __restrict__ w01,
    const float* __restrict__ w10, const float* __restrict__ w11,
    float* __restrict__ W) {
    int i = blockIdx.x * 256 + threadIdx.x;
    const float inv_fan = 0.10206207261596577f;  // 1/sqrt(96)
    const float IS3 = 0.5773502691896258f;
    if (i < 9216) {
        int u = i / 96;
        float sc = inv_fan * (u < 64 ? w00[u] : IS3 * w11[u - 64]);
        W[i] = Wls[i] * sc;
    } else if (i < 12288) {
        int j = i - 9216; int u = j / 32;
        float sc = inv_fan * (u < 64 ? w01[u] : w10[u - 64]);
        W[i] = Wlv[j] * sc;
    } else if (i < 18432) {
        W[i] = W000[i - 12288] * 0.08838834764831845f;   // inv2/sqrt(64)
    } else if (i < 21504) {
        W[i] = W110[i - 18432] * (0.125f * IS3);         // inv2/sqrt(32) * IS3
    } else if (i < 23552) {
        W[i] = W011[i - 21504] * 0.08838834764831845f;   // inv2/sqrt(64)
    } else {
        W[i] = W101[i - 23552] * 0.125f;                 // inv2/sqrt(32)
    }
}

// ---------------- K5: per-node fused update (lane = node) --------------------
__global__ __launch_bounds__(256) void node_k(
    const u16* __restrict__ msgT,     // [160][N] bf16 (already /sqrt5)
    const u16* __restrict__ featsT,   // [160][N] bf16
    const float* __restrict__ attrs,  // [N][4] f32
    const float* __restrict__ W,      // pre-scaled weights f32
    float* __restrict__ out)          // [N][160] f32
{
    int n = blockIdx.x * 256 + threadIdx.x;
    bool active = (n < Nn);
    if (!active) n = Nn - 1;

    const float* Wls = W;
    const float* Wlv = W + 9216;
    const float* W000 = W + 12288;
    const float* W110 = W + 18432;
    const float* W011 = W + 21504;
    const float* W101 = W + 23552;

    float a_s, av[3];
    {
        float4 a = *reinterpret_cast<const float4*>(attrs + (size_t)n * 4);
        a_s = a.x; av[0] = a.y; av[1] = a.z; av[2] = a.w;
    }

    float sg[32];

    // ---- h_s in three w-blocks of 32 (keeps VGPR pressure low) ----
    for (int wb = 0; wb < 3; ++wb) {
        float acc[32];
        #pragma unroll
        for (int w = 0; w < 32; ++w) acc[w] = 0.f;
        const float* R1 = Wls + wb * 32;
        const float* R2 = W000 + wb * 32;
        const float* R3 = W110 + wb * 32;
        for (int u = 0; u < 64; ++u) {
            float msa = bf2f(msgT[(size_t)u * Nn + n]) * a_s;
            float xsa = bf2f(featsT[(size_t)u * Nn + n]) * a_s;
            const float* r1 = R1 + u * 96;
            const float* r2 = R2 + u * 96;
            #pragma unroll
            for (int w = 0; w < 32; ++w) acc[w] += msa * r1[w] + xsa * r2[w];
        }
        for (int j = 0; j < 32; ++j) {
            size_t d = (size_t)(64 + 3 * j) * Nn + n;
            float dv = bf2f(msgT[d]) * av[0] + bf2f(msgT[d + Nn]) * av[1]
                     + bf2f(msgT[d + 2 * Nn]) * av[2];
            float dx = bf2f(featsT[d]) * av[0] + bf2f(featsT[d + Nn]) * av[1]
                     + bf2f(featsT[d + 2 * Nn]) * av[2];
            const float* r1 = R1 + (64 + j) * 96;
            const float* r2 = R3 + j * 96;
            #pragma unroll
            for (int w = 0; w < 32; ++w) acc[w] += dv * r1[w] + dx * r2[w];
        }
        if (wb < 2) {
            #pragma unroll
            for (int w = 0; w < 32; ++w) {
                float h = acc[w];
                float o = h / (1.f + __expf(-h));   // silu
                if (active) out[(size_t)n * DIM + wb * 32 + w] = o;
            }
        } else {
            #pragma unroll
            for (int w = 0; w < 32; ++w) sg[w] = 1.f / (1.f + __expf(-acc[w])); // gates
        }
    }

    // ---- ss[w] = sum_u ms[u]*Wlv'[u][w] + xs[u]*W011'[u][w]  (w<32) ----
    float ss[32];
    #pragma unroll
    for (int w = 0; w < 32; ++w) ss[w] = 0.f;
    for (int u = 0; u < 64; ++u) {
        float m = bf2f(msgT[(size_t)u * Nn + n]);
        float x = bf2f(featsT[(size_t)u * Nn + n]);
        const float* r1 = Wlv + u * 32;
        const float* r2 = W011 + u * 32;
        #pragma unroll
        for (int w = 0; w < 32; ++w) ss[w] += m * r1[w] + x * r2[w];
    }

    // ---- h_v per component c ----
    #pragma unroll
    for (int c = 0; c < 3; ++c) {
        float hv[32];
        #pragma unroll
        for (int w = 0; w < 32; ++w) hv[w] = av[c] * ss[w];
        for (int j = 0; j < 32; ++j) {
            size_t d = (size_t)(64 + 3 * j + c) * Nn + n;
            float m = bf2f(msgT[d]) * a_s;
            float x = bf2f(featsT[d]) * a_s;
            const float* r1 = Wlv + (64 + j) * 32;
            const float* r2 = W101 + j * 32;
            #pragma unroll
            for (int w = 0; w < 32; ++w) hv[w] += m * r1[w] + x * r2[w];
        }
        if (active) {
            #pragma unroll
            for (int w = 0; w < 32; ++w)
                out[(size_t)n * DIM + 64 + 3 * w + c] = sg[w] * hv[w];
        }
    }
}

extern "C" void kernel_launch(void* const* d_in, const int* in_sizes, int n_in,
                              void* d_out, int out_size, void* d_ws, size_t ws_size,
                              hipStream_t stream) {
    const float* feats = (const float*)d_in[0];
    const float* attrs = (const float*)d_in[1];
    const float* em    = (const float*)d_in[2];
    const int*   ei    = (const int*)d_in[3];
    const float* w00   = (const float*)d_in[4];
    const float* w01   = (const float*)d_in[5];
    const float* w10   = (const float*)d_in[6];
    const float* w11   = (const float*)d_in[7];
    const float* Wls   = (const float*)d_in[8];
    const float* Wlv   = (const float*)d_in[9];
    const float* W000  = (const float*)d_in[10];
    const float* W110  = (const float*)d_in[11];
    const float* W011  = (const float*)d_in[12];
    const float* W101  = (const float*)d_in[13];

    char* ws = (char*)d_ws;
    float* msg    = (float*)(ws);                 // 64,000,000 B  [N][160] f32
    u16*   msgT   = (u16*)  (ws + 64000000);      // 32,000,000 B  [160][N] bf16
    u16*   featsT = (u16*)  (ws + 96000000);      // 32,000,000 B  [160][N] bf16
    float* W      = (float*)(ws + 128000000);     // 98,304 B      pre-scaled weights

    hipMemsetAsync(msg, 0, (size_t)Nn * DIM * sizeof(float), stream);

    scatter_k<<<(Ee * 40 + 255) / 256, 256, 0, stream>>>(em, ei, msg);

    dim3 tb(32, 32);
    transpose_f2b_k<<<dim3(Nn / 32, DIM / 32), tb, 0, stream>>>(msg, msgT);
    transpose_f2b_k<<<dim3(Nn / 32, DIM / 32), tb, 0, stream>>>(feats, featsT);

    prep_weights_k<<<96, 256, 0, stream>>>(Wls, Wlv, W000, W110, W011, W101,
                                           w00, w01, w10, w11, W);

    node_k<<<(Nn + 255) / 256, 256, 0, stream>>>(msgT, featsT, attrs, W, (float*)d_out);
}

// Round 3
// 886.550 us; speedup vs baseline: 1.9627x; 1.9627x over previous
//
#include <hip/hip_runtime.h>

typedef unsigned short u16;
typedef unsigned int u32;

#define Nn 100000
#define Ee 500000
#define DIM 160
#define CAP 48

__device__ __forceinline__ float bf2f(u16 u) {
    return __uint_as_float(((u32)u) << 16);
}
__device__ __forceinline__ u16 f2bf(float f) {
    u32 i = __float_as_uint(f);
    return (u16)((i + 0x7FFFu + ((i >> 16) & 1u)) >> 16);
}

// ---------------- K1: histogram + bucket fill (one pass) ---------------------
__global__ __launch_bounds__(256) void hist_fill_k(const int* __restrict__ ei,
                                                   int* __restrict__ cnt,
                                                   int* __restrict__ bucket) {
    int e = blockIdx.x * 256 + threadIdx.x;
    if (e >= Ee) return;
    int dst = ei[Ee + e];                 // edge_index row 1 (dst)
    int pos = atomicAdd(&cnt[dst], 1);
    if (pos < CAP) bucket[(size_t)dst * CAP + pos] = e;
}

// ---------------- K2: gather segment-sum (wave per node) ---------------------
__global__ __launch_bounds__(256) void gather_k(const float* __restrict__ em,
                                                const int* __restrict__ bucket,
                                                const int* __restrict__ cnt,
                                                float* __restrict__ msg) {
    int gid = blockIdx.x * 256 + threadIdx.x;
    int n = gid >> 6;
    int lane = gid & 63;
    if (n >= Nn) return;
    int deg = cnt[n];
    if (deg > CAP) deg = CAP;
    const int* base = bucket + (size_t)n * CAP;
    float a0 = 0.f, a1 = 0.f, a2 = 0.f;
    for (int i = 0; i < deg; ++i) {
        int e = base[i];                          // wave-uniform broadcast load
        const float* r = em + (size_t)e * DIM;
        a0 += r[lane];
        a1 += r[64 + lane];
        if (lane < 32) a2 += r[128 + lane];
    }
    const float s = 0.4472135954999579f;          // 1/sqrt(5)
    float* q = msg + (size_t)n * DIM;
    q[lane] = a0 * s;
    q[64 + lane] = a1 * s;
    if (lane < 32) q[128 + lane] = a2 * s;
}

// ---------------- K3: transpose [N][160] f32 -> [160][N] bf16 ----------------
__global__ void transpose_f2b_k(const float* __restrict__ in, u16* __restrict__ outp) {
    __shared__ float t[32][33];
    int r0 = blockIdx.x * 32, c0 = blockIdx.y * 32;
    int tx = threadIdx.x, ty = threadIdx.y;
    t[ty][tx] = in[(size_t)(r0 + ty) * DIM + c0 + tx];
    __syncthreads();
    outp[(size_t)(c0 + ty) * Nn + r0 + tx] = f2bf(t[tx][ty]);
}

// ---------------- K4: pre-scale + fuse all weight factors (f32) --------------
// Layout in W (f32): Wls' [96][96] @0, Wlv' [96][32] @9216, W000' [64][96] @12288,
//                    W110' [32][96] @18432, W011' [64][32] @21504, W101' [32][32] @23552
__global__ __launch_bounds__(256) void prep_weights_k(
    const float* __restrict__ Wls, const float* __restrict__ Wlv,
    const float* __restrict__ W000, const float* __restrict__ W110,
    const float* __restrict__ W011, const float* __restrict__ W101,
    const float* __restrict__ w00, const float* __restrict__ w01,
    const float* __restrict__ w10, const float* __restrict__ w11,
    float* __restrict__ W) {
    int i = blockIdx.x * 256 + threadIdx.x;
    const float inv_fan = 0.10206207261596577f;  // 1/sqrt(96)
    const float IS3 = 0.5773502691896258f;
    if (i < 9216) {
        int u = i / 96;
        float sc = inv_fan * (u < 64 ? w00[u] : IS3 * w11[u - 64]);
        W[i] = Wls[i] * sc;
    } else if (i < 12288) {
        int j = i - 9216; int u = j / 32;
        float sc = inv_fan * (u < 64 ? w01[u] : w10[u - 64]);
        W[i] = Wlv[j] * sc;
    } else if (i < 18432) {
        W[i] = W000[i - 12288] * 0.08838834764831845f;   // inv2/sqrt(64)
    } else if (i < 21504) {
        W[i] = W110[i - 18432] * (0.125f * IS3);         // inv2/sqrt(32) * IS3
    } else if (i < 23552) {
        W[i] = W011[i - 21504] * 0.08838834764831845f;   // inv2/sqrt(64)
    } else {
        W[i] = W101[i - 23552] * 0.125f;                 // inv2/sqrt(32)
    }
}

// ---------------- K5: per-node fused update (lane = node) --------------------
__global__ __launch_bounds__(256) void node_k(
    const u16* __restrict__ msgT,     // [160][N] bf16 (already /sqrt5)
    const u16* __restrict__ featsT,   // [160][N] bf16
    const float* __restrict__ attrs,  // [N][4] f32
    const float* __restrict__ W,      // pre-scaled weights f32
    float* __restrict__ out)          // [N][160] f32
{
    int n = blockIdx.x * 256 + threadIdx.x;
    bool active = (n < Nn);
    if (!active) n = Nn - 1;

    const float* Wls = W;
    const float* Wlv = W + 9216;
    const float* W000 = W + 12288;
    const float* W110 = W + 18432;
    const float* W011 = W + 21504;
    const float* W101 = W + 23552;

    float a_s, av[3];
    {
        float4 a = *reinterpret_cast<const float4*>(attrs + (size_t)n * 4);
        a_s = a.x; av[0] = a.y; av[1] = a.z; av[2] = a.w;
    }

    float sg[32];

    // ---- h_s in three w-blocks of 32 (keeps VGPR pressure low) ----
    for (int wb = 0; wb < 3; ++wb) {
        float acc[32];
        #pragma unroll
        for (int w = 0; w < 32; ++w) acc[w] = 0.f;
        const float* R1 = Wls + wb * 32;
        const float* R2 = W000 + wb * 32;
        const float* R3 = W110 + wb * 32;
        for (int u = 0; u < 64; ++u) {
            float msa = bf2f(msgT[(size_t)u * Nn + n]) * a_s;
            float xsa = bf2f(featsT[(size_t)u * Nn + n]) * a_s;
            const float* r1 = R1 + u * 96;
            const float* r2 = R2 + u * 96;
            #pragma unroll
            for (int w = 0; w < 32; ++w) acc[w] += msa * r1[w] + xsa * r2[w];
        }
        for (int j = 0; j < 32; ++j) {
            size_t d = (size_t)(64 + 3 * j) * Nn + n;
            float dv = bf2f(msgT[d]) * av[0] + bf2f(msgT[d + Nn]) * av[1]
                     + bf2f(msgT[d + 2 * Nn]) * av[2];
            float dx = bf2f(featsT[d]) * av[0] + bf2f(featsT[d + Nn]) * av[1]
                     + bf2f(featsT[d + 2 * Nn]) * av[2];
            const float* r1 = R1 + (64 + j) * 96;
            const float* r2 = R3 + j * 96;
            #pragma unroll
            for (int w = 0; w < 32; ++w) acc[w] += dv * r1[w] + dx * r2[w];
        }
        if (wb < 2) {
            #pragma unroll
            for (int w = 0; w < 32; ++w) {
                float h = acc[w];
                float o = h / (1.f + __expf(-h));   // silu
                if (active) out[(size_t)n * DIM + wb * 32 + w] = o;
            }
        } else {
            #pragma unroll
            for (int w = 0; w < 32; ++w) sg[w] = 1.f / (1.f + __expf(-acc[w])); // gates
        }
    }

    // ---- ss[w] = sum_u ms[u]*Wlv'[u][w] + xs[u]*W011'[u][w]  (w<32) ----
    float ss[32];
    #pragma unroll
    for (int w = 0; w < 32; ++w) ss[w] = 0.f;
    for (int u = 0; u < 64; ++u) {
        float m = bf2f(msgT[(size_t)u * Nn + n]);
        float x = bf2f(featsT[(size_t)u * Nn + n]);
        const float* r1 = Wlv + u * 32;
        const float* r2 = W011 + u * 32;
        #pragma unroll
        for (int w = 0; w < 32; ++w) ss[w] += m * r1[w] + x * r2[w];
    }

    // ---- h_v per component c ----
    #pragma unroll
    for (int c = 0; c < 3; ++c) {
        float hv[32];
        #pragma unroll
        for (int w = 0; w < 32; ++w) hv[w] = av[c] * ss[w];
        for (int j = 0; j < 32; ++j) {
            size_t d = (size_t)(64 + 3 * j + c) * Nn + n;
            float m = bf2f(msgT[d]) * a_s;
            float x = bf2f(featsT[d]) * a_s;
            const float* r1 = Wlv + (64 + j) * 32;
            const float* r2 = W101 + j * 32;
            #pragma unroll
            for (int w = 0; w < 32; ++w) hv[w] += m * r1[w] + x * r2[w];
        }
        if (active) {
            #pragma unroll
            for (int w = 0; w < 32; ++w)
                out[(size_t)n * DIM + 64 + 3 * w + c] = sg[w] * hv[w];
        }
    }
}

extern "C" void kernel_launch(void* const* d_in, const int* in_sizes, int n_in,
                              void* d_out, int out_size, void* d_ws, size_t ws_size,
                              hipStream_t stream) {
    const float* feats = (const float*)d_in[0];
    const float* attrs = (const float*)d_in[1];
    const float* em    = (const float*)d_in[2];
    const int*   ei    = (const int*)d_in[3];
    const float* w00   = (const float*)d_in[4];
    const float* w01   = (const float*)d_in[5];
    const float* w10   = (const float*)d_in[6];
    const float* w11   = (const float*)d_in[7];
    const float* Wls   = (const float*)d_in[8];
    const float* Wlv   = (const float*)d_in[9];
    const float* W000  = (const float*)d_in[10];
    const float* W110  = (const float*)d_in[11];
    const float* W011  = (const float*)d_in[12];
    const float* W101  = (const float*)d_in[13];

    char* ws = (char*)d_ws;
    int*   bucket = (int*)  (ws);                  // 19,200,000 B [N][48] int
    int*   cnt    = (int*)  (ws + 19200000);       //    400,000 B [N] int
    float* msg    = (float*)(ws + 19600000);       // 64,000,000 B [N][160] f32
    u16*   msgT   = (u16*)  (ws + 83600000);       // 32,000,000 B [160][N] bf16
    u16*   featsT = (u16*)  (ws + 115600000);      // 32,000,000 B [160][N] bf16
    float* W      = (float*)(ws + 147600000);      //     98,304 B weights

    hipMemsetAsync(cnt, 0, Nn * sizeof(int), stream);

    hist_fill_k<<<(Ee + 255) / 256, 256, 0, stream>>>(ei, cnt, bucket);

    gather_k<<<(Nn * 64 + 255) / 256, 256, 0, stream>>>(em, bucket, cnt, msg);

    dim3 tb(32, 32);
    transpose_f2b_k<<<dim3(Nn / 32, DIM / 32), tb, 0, stream>>>(msg, msgT);
    transpose_f2b_k<<<dim3(Nn / 32, DIM / 32), tb, 0, stream>>>(feats, featsT);

    prep_weights_k<<<96, 256, 0, stream>>>(Wls, Wlv, W000, W110, W011, W101,
                                           w00, w01, w10, w11, W);

    node_k<<<(Nn + 255) / 256, 256, 0, stream>>>(msgT, featsT, attrs, W, (float*)d_out);
}